// Round 9
// baseline (529.017 us; speedup 1.0000x reference)
//
#include <hip/hip_runtime.h>

// Problem constants: S_SENT=256, L=128, D=768, C=21
#define NS 32768
#define NQ 32768
#define DIM 768
#define NC 21

// Workspace float layout
#define WS_CS   0          // class_sum [21*768]
#define WS_CNT  16128      // counts    [21]
#define WS_ZERO 16149      // floats to zero

// full-wave (64-lane) sum, result replicated in every lane.
// xor32 + xor16 cross-lane, then 4 DPP row_ror adds (VALU pipe).
__device__ inline float wave_allsum(float x) {
    x += __shfl_xor(x, 32);
    x += __shfl_xor(x, 16);
    int xi;
    xi = __builtin_amdgcn_update_dpp(0, __float_as_int(x), 0x128, 0xF, 0xF, false); // row_ror:8
    x += __int_as_float(xi);
    xi = __builtin_amdgcn_update_dpp(0, __float_as_int(x), 0x124, 0xF, 0xF, false); // row_ror:4
    x += __int_as_float(xi);
    xi = __builtin_amdgcn_update_dpp(0, __float_as_int(x), 0x122, 0xF, 0xF, false); // row_ror:2
    x += __int_as_float(xi);
    xi = __builtin_amdgcn_update_dpp(0, __float_as_int(x), 0x121, 0xF, 0xF, false); // row_ror:1
    x += __int_as_float(xi);
    return x;
}

// ---------------- Kernel 0: per-class masked counts ----------------
__global__ __launch_bounds__(256) void k_counts(const int* __restrict__ lab,
                                                const int* __restrict__ msk,
                                                float* __restrict__ ws) {
    __shared__ int cnt[NC];
    int tid = threadIdx.x;
    if (tid < NC) cnt[tid] = 0;
    __syncthreads();
    int idx = blockIdx.x * 256 + tid;
    int stride = gridDim.x * 256;
    for (int i = idx; i < NS; i += stride) {
        if (msk[i]) atomicAdd(&cnt[lab[i]], 1);
    }
    __syncthreads();
    if (tid < NC && cnt[tid] > 0) atomicAdd(&ws[WS_CNT + tid], (float)cnt[tid]);
}

// ---------------- Kernel 1: class sums, register accumulators ----------------
// 256 blocks x 768 threads (12 waves). Thread owns column tid; block owns 128
// tokens. Class select is wave-uniform scalar (readfirstlane -> s_cmp/s_cselect)
// feeding one v_fma per class: no LDS RMW chain in the loop.
__global__ __launch_bounds__(768) void k_classsum(const float* __restrict__ emb,
                                                  const int* __restrict__ lab,
                                                  const int* __restrict__ msk,
                                                  float* __restrict__ ws) {
    __shared__ int lmc[128];   // label if masked else 255
    int tid = threadIdx.x;
    int t0 = blockIdx.x * 128;
    if (tid < 128) {
        int i = t0 + tid;
        lmc[tid] = msk[i] ? lab[i] : 255;
    }
    __syncthreads();

    float acc[NC];
#pragma unroll
    for (int c = 0; c < NC; ++c) acc[c] = 0.f;

    const float* ecol = emb + (size_t)t0 * DIM + tid;

    auto process = [&](int tb, float v0, float v1, float v2, float v3) {
        int cu0 = __builtin_amdgcn_readfirstlane(lmc[tb + 0]);
        int cu1 = __builtin_amdgcn_readfirstlane(lmc[tb + 1]);
        int cu2 = __builtin_amdgcn_readfirstlane(lmc[tb + 2]);
        int cu3 = __builtin_amdgcn_readfirstlane(lmc[tb + 3]);
#pragma unroll
        for (int c = 0; c < NC; ++c) {
            float s0 = (cu0 == c) ? 1.f : 0.f;
            float s1 = (cu1 == c) ? 1.f : 0.f;
            float s2 = (cu2 == c) ? 1.f : 0.f;
            float s3 = (cu3 == c) ? 1.f : 0.f;
            acc[c] = fmaf(s0, v0, acc[c]);
            acc[c] = fmaf(s1, v1, acc[c]);
            acc[c] = fmaf(s2, v2, acc[c]);
            acc[c] = fmaf(s3, v3, acc[c]);
        }
    };

    // 32 groups of 4 tokens, one-group load lookahead (8 loads in flight)
    float v0 = ecol[(size_t)0 * DIM];
    float v1 = ecol[(size_t)1 * DIM];
    float v2 = ecol[(size_t)2 * DIM];
    float v3 = ecol[(size_t)3 * DIM];
    for (int g = 0; g < 31; ++g) {
        int tb = g * 4;
        float n0 = ecol[(size_t)(tb + 4) * DIM];
        float n1 = ecol[(size_t)(tb + 5) * DIM];
        float n2 = ecol[(size_t)(tb + 6) * DIM];
        float n3 = ecol[(size_t)(tb + 7) * DIM];
        process(tb, v0, v1, v2, v3);
        v0 = n0; v1 = n1; v2 = n2; v3 = n3;
    }
    process(124, v0, v1, v2, v3);

    // flush: coalesced atomics, one address owner per (c, col) per block
#pragma unroll
    for (int c = 0; c < NC; ++c) {
        atomicAdd(&ws[WS_CS + c * DIM + tid], acc[c]);
    }
}

// ---------------- Kernel 2: proto-finalize + logits + argmax ----------------
// 512 blocks x 256 threads (4 waves), 64 rows/block, 4 rows per wave-iter.
// Protos staged once into LDS (63 KB -> 2 blocks/CU), conflict-free b128 reads,
// each proto read feeds 16 FMAs. Per-(row,class) reduce = 2 shfl + 4 DPP.
#define LB 64
__global__ __launch_bounds__(256, 2) void k_logits(const float* __restrict__ qemb,
                                                   const float* __restrict__ ws,
                                                   float* __restrict__ out) {
    __shared__ __align__(16) float pshared[NC * DIM];   // 63 KB
    __shared__ float pnorm[NC];
    __shared__ float crecip[NC + 3];
    int tid = threadIdx.x;

    if (tid < NC) {
        float cv = ws[WS_CNT + tid];
        crecip[tid] = (cv > 0.f) ? (1.f / cv) : 0.f;
    }
    __syncthreads();

    // stage protos (scale class_sum by 1/count while staging)
    {
        const float4* cs4 = (const float4*)(ws + WS_CS);
        float4* ps4 = (float4*)pshared;
#pragma unroll
        for (int k = 0; k < 16; ++k) {
            int i4 = tid + k * 256;
            if (i4 < NC * DIM / 4) {
                float4 v = cs4[i4];
                float r = crecip[i4 / 192];   // class = 4*i4/768
                v.x *= r; v.y *= r; v.z *= r; v.w *= r;
                ps4[i4] = v;
            }
        }
    }
    __syncthreads();

    int wid = tid >> 6, lane = tid & 63;

    // pnorm[c] = ||proto_c||^2 ; wave w handles classes w, w+4, ...
    for (int c = wid; c < NC; c += 4) {
        const float4* pr = (const float4*)(pshared + c * DIM);
        float s = 0.f;
#pragma unroll
        for (int j = 0; j < 3; ++j) {
            float4 p = pr[lane * 3 + j];
            s += p.x * p.x + p.y * p.y + p.z * p.z + p.w * p.w;
        }
        s = wave_allsum(s);
        if (lane == 0) pnorm[c] = s;
    }
    __syncthreads();

    const float4* q4 = (const float4*)qemb;
    int rbase = blockIdx.x * LB + wid * 16;

    for (int it = 0; it < 4; ++it) {
        int r0 = rbase + it * 4;

        float4 q[4][3];
#pragma unroll
        for (int r = 0; r < 4; ++r) {
#pragma unroll
            for (int s = 0; s < 3; ++s) {
                q[r][s] = q4[(size_t)(r0 + r) * (DIM / 4) + s * 64 + lane];
            }
        }

        float qn[4];
#pragma unroll
        for (int r = 0; r < 4; ++r) {
            float t = 0.f;
#pragma unroll
            for (int s = 0; s < 3; ++s) {
                float4 a = q[r][s];
                t += a.x * a.x + a.y * a.y + a.z * a.z + a.w * a.w;
            }
            qn[r] = wave_allsum(t);
        }

        float myv[4], best[4];
        int bi[4];
#pragma unroll
        for (int r = 0; r < 4; ++r) { myv[r] = 0.f; best[r] = -3.4e38f; bi[r] = 0; }

#pragma unroll
        for (int c = 0; c < NC; ++c) {
            const float4* pr = (const float4*)(pshared + c * DIM);
            float4 p0 = pr[lane], p1 = pr[lane + 64], p2 = pr[lane + 128];
            float pn = pnorm[c];
#pragma unroll
            for (int r = 0; r < 4; ++r) {
                float d = q[r][0].x * p0.x + q[r][0].y * p0.y + q[r][0].z * p0.z + q[r][0].w * p0.w
                        + q[r][1].x * p1.x + q[r][1].y * p1.y + q[r][1].z * p1.z + q[r][1].w * p1.w
                        + q[r][2].x * p2.x + q[r][2].y * p2.y + q[r][2].z * p2.z + q[r][2].w * p2.w;
                d = wave_allsum(d);
                float lc = 2.f * d - pn;            // qn deferred (uniform over c)
                myv[r] = (lane == c) ? lc : myv[r];
                if (lc > best[r]) { best[r] = lc; bi[r] = c; }   // first max wins
            }
        }

#pragma unroll
        for (int r = 0; r < 4; ++r) {
            if (lane < NC) out[(size_t)(r0 + r) * NC + lane] = myv[r] - qn[r];
            if (lane == 0) out[(size_t)NQ * NC + (r0 + r)] = (float)bi[r];
        }
    }
}

extern "C" void kernel_launch(void* const* d_in, const int* in_sizes, int n_in,
                              void* d_out, int out_size, void* d_ws, size_t ws_size,
                              hipStream_t stream) {
    const float* semb = (const float*)d_in[0];
    const float* qemb = (const float*)d_in[1];
    const int*   lab  = (const int*)d_in[2];
    const int*   msk  = (const int*)d_in[3];
    float* ws  = (float*)d_ws;
    float* out = (float*)d_out;

    hipMemsetAsync(d_ws, 0, WS_ZERO * sizeof(float), stream);
    k_counts<<<64, 256, 0, stream>>>(lab, msk, ws);
    k_classsum<<<256, 768, 0, stream>>>(semb, lab, msk, ws);
    k_logits<<<NQ / LB, 256, 0, stream>>>(qemb, ws, out);
}

// Round 11
// 409.103 us; speedup vs baseline: 1.2931x; 1.2931x over previous
//
#include <hip/hip_runtime.h>

// Problem constants: S_SENT=256, L=128, D=768, C=21
#define NS 32768
#define NQ 32768
#define DIM 768
#define NC 21

// Workspace float layout
#define WS_CS   0          // class_sum [21*768]
#define WS_CNT  16128      // counts    [21]
#define WS_ZERO 16149      // floats to zero

// full-wave (64-lane) sum, result replicated in every lane.
// xor32 + xor16 cross-lane, then 4 DPP row_ror adds (VALU pipe).
__device__ inline float wave_allsum(float x) {
    x += __shfl_xor(x, 32);
    x += __shfl_xor(x, 16);
    int xi;
    xi = __builtin_amdgcn_update_dpp(0, __float_as_int(x), 0x128, 0xF, 0xF, false); // row_ror:8
    x += __int_as_float(xi);
    xi = __builtin_amdgcn_update_dpp(0, __float_as_int(x), 0x124, 0xF, 0xF, false); // row_ror:4
    x += __int_as_float(xi);
    xi = __builtin_amdgcn_update_dpp(0, __float_as_int(x), 0x122, 0xF, 0xF, false); // row_ror:2
    x += __int_as_float(xi);
    xi = __builtin_amdgcn_update_dpp(0, __float_as_int(x), 0x121, 0xF, 0xF, false); // row_ror:1
    x += __int_as_float(xi);
    return x;
}

// ---------------- Kernel 0: per-class masked counts (unchanged) ----------------
__global__ __launch_bounds__(256) void k_counts(const int* __restrict__ lab,
                                                const int* __restrict__ msk,
                                                float* __restrict__ ws) {
    __shared__ int cnt[NC];
    int tid = threadIdx.x;
    if (tid < NC) cnt[tid] = 0;
    __syncthreads();
    int idx = blockIdx.x * 256 + tid;
    int stride = gridDim.x * 256;
    for (int i = idx; i < NS; i += stride) {
        if (msk[i]) atomicAdd(&cnt[lab[i]], 1);
    }
    __syncthreads();
    if (tid < NC && cnt[tid] > 0) atomicAdd(&ws[WS_CNT + tid], (float)cnt[tid]);
}

// ---------------- Kernel 1: class sums (byte-identical to round 9) ----------------
// Kept unchanged on purpose: it has never been profiled (always below the
// top-5 cutoff). Once k_logits shrinks, this tops the counter table and we
// get real evidence before touching it.
__global__ __launch_bounds__(768) void k_classsum(const float* __restrict__ emb,
                                                  const int* __restrict__ lab,
                                                  const int* __restrict__ msk,
                                                  float* __restrict__ ws) {
    __shared__ int lmc[128];   // label if masked else 255
    int tid = threadIdx.x;
    int t0 = blockIdx.x * 128;
    if (tid < 128) {
        int i = t0 + tid;
        lmc[tid] = msk[i] ? lab[i] : 255;
    }
    __syncthreads();

    float acc[NC];
#pragma unroll
    for (int c = 0; c < NC; ++c) acc[c] = 0.f;

    const float* ecol = emb + (size_t)t0 * DIM + tid;

    auto process = [&](int tb, float v0, float v1, float v2, float v3) {
        int cu0 = __builtin_amdgcn_readfirstlane(lmc[tb + 0]);
        int cu1 = __builtin_amdgcn_readfirstlane(lmc[tb + 1]);
        int cu2 = __builtin_amdgcn_readfirstlane(lmc[tb + 2]);
        int cu3 = __builtin_amdgcn_readfirstlane(lmc[tb + 3]);
#pragma unroll
        for (int c = 0; c < NC; ++c) {
            float s0 = (cu0 == c) ? 1.f : 0.f;
            float s1 = (cu1 == c) ? 1.f : 0.f;
            float s2 = (cu2 == c) ? 1.f : 0.f;
            float s3 = (cu3 == c) ? 1.f : 0.f;
            acc[c] = fmaf(s0, v0, acc[c]);
            acc[c] = fmaf(s1, v1, acc[c]);
            acc[c] = fmaf(s2, v2, acc[c]);
            acc[c] = fmaf(s3, v3, acc[c]);
        }
    };

    float v0 = ecol[(size_t)0 * DIM];
    float v1 = ecol[(size_t)1 * DIM];
    float v2 = ecol[(size_t)2 * DIM];
    float v3 = ecol[(size_t)3 * DIM];
    for (int g = 0; g < 31; ++g) {
        int tb = g * 4;
        float n0 = ecol[(size_t)(tb + 4) * DIM];
        float n1 = ecol[(size_t)(tb + 5) * DIM];
        float n2 = ecol[(size_t)(tb + 6) * DIM];
        float n3 = ecol[(size_t)(tb + 7) * DIM];
        process(tb, v0, v1, v2, v3);
        v0 = n0; v1 = n1; v2 = n2; v3 = n3;
    }
    process(124, v0, v1, v2, v3);

#pragma unroll
    for (int c = 0; c < NC; ++c) {
        atomicAdd(&ws[WS_CS + c * DIM + tid], acc[c]);
    }
}

// ---------------- Kernel 2: proto-finalize + logits + argmax (spill fix) ----------------
// 512 blocks x 256 threads. Protos in LDS (63 KB, 2 blocks/CU). CHANGES vs r9:
// (a) #pragma unroll 1 on the row-group loop — blocks the auto-unroll that
//     merged 4 iterations' q-fragments into one live range and spilled;
// (b) 2 rows per group (q = 24 VGPRs live) — spill-proof under any cap.
#define LB 64
__global__ __launch_bounds__(256, 2) void k_logits(const float* __restrict__ qemb,
                                                   const float* __restrict__ ws,
                                                   float* __restrict__ out) {
    __shared__ __align__(16) float pshared[NC * DIM];   // 63 KB
    __shared__ float pnorm[NC];
    __shared__ float crecip[NC + 3];
    int tid = threadIdx.x;

    if (tid < NC) {
        float cv = ws[WS_CNT + tid];
        crecip[tid] = (cv > 0.f) ? (1.f / cv) : 0.f;
    }
    __syncthreads();

    // stage protos (scale class_sum by 1/count while staging)
    {
        const float4* cs4 = (const float4*)(ws + WS_CS);
        float4* ps4 = (float4*)pshared;
#pragma unroll
        for (int k = 0; k < 16; ++k) {
            int i4 = tid + k * 256;
            if (i4 < NC * DIM / 4) {
                float4 v = cs4[i4];
                float r = crecip[i4 / 192];   // class = 4*i4/768
                v.x *= r; v.y *= r; v.z *= r; v.w *= r;
                ps4[i4] = v;
            }
        }
    }
    __syncthreads();

    int wid = tid >> 6, lane = tid & 63;

    // pnorm[c] = ||proto_c||^2
    for (int c = wid; c < NC; c += 4) {
        const float4* pr = (const float4*)(pshared + c * DIM);
        float s = 0.f;
#pragma unroll
        for (int j = 0; j < 3; ++j) {
            float4 p = pr[lane * 3 + j];
            s += p.x * p.x + p.y * p.y + p.z * p.z + p.w * p.w;
        }
        s = wave_allsum(s);
        if (lane == 0) pnorm[c] = s;
    }
    __syncthreads();

    const float4* q4 = (const float4*)qemb;
    int rbase = blockIdx.x * LB + wid * 16;

#pragma unroll 1
    for (int it = 0; it < 8; ++it) {          // 2 rows per group, 8 groups
        int r0 = rbase + it * 2;

        float4 q[2][3];
#pragma unroll
        for (int r = 0; r < 2; ++r) {
#pragma unroll
            for (int s = 0; s < 3; ++s) {
                q[r][s] = q4[(size_t)(r0 + r) * (DIM / 4) + s * 64 + lane];
            }
        }

        float qn[2];
#pragma unroll
        for (int r = 0; r < 2; ++r) {
            float t = 0.f;
#pragma unroll
            for (int s = 0; s < 3; ++s) {
                float4 a = q[r][s];
                t += a.x * a.x + a.y * a.y + a.z * a.z + a.w * a.w;
            }
            qn[r] = wave_allsum(t);
        }

        float myv[2], best[2];
        int bi[2];
#pragma unroll
        for (int r = 0; r < 2; ++r) { myv[r] = 0.f; best[r] = -3.4e38f; bi[r] = 0; }

#pragma unroll
        for (int c = 0; c < NC; ++c) {
            const float4* pr = (const float4*)(pshared + c * DIM);
            float4 p0 = pr[lane], p1 = pr[lane + 64], p2 = pr[lane + 128];
            float pn = pnorm[c];
#pragma unroll
            for (int r = 0; r < 2; ++r) {
                float d = q[r][0].x * p0.x + q[r][0].y * p0.y + q[r][0].z * p0.z + q[r][0].w * p0.w
                        + q[r][1].x * p1.x + q[r][1].y * p1.y + q[r][1].z * p1.z + q[r][1].w * p1.w
                        + q[r][2].x * p2.x + q[r][2].y * p2.y + q[r][2].z * p2.z + q[r][2].w * p2.w;
                d = wave_allsum(d);
                float lc = 2.f * d - pn;            // qn deferred (uniform over c)
                myv[r] = (lane == c) ? lc : myv[r];
                if (lc > best[r]) { best[r] = lc; bi[r] = c; }   // first max wins
            }
        }

#pragma unroll
        for (int r = 0; r < 2; ++r) {
            if (lane < NC) out[(size_t)(r0 + r) * NC + lane] = myv[r] - qn[r];
            if (lane == 0) out[(size_t)NQ * NC + (r0 + r)] = (float)bi[r];
        }
    }
}

extern "C" void kernel_launch(void* const* d_in, const int* in_sizes, int n_in,
                              void* d_out, int out_size, void* d_ws, size_t ws_size,
                              hipStream_t stream) {
    const float* semb = (const float*)d_in[0];
    const float* qemb = (const float*)d_in[1];
    const int*   lab  = (const int*)d_in[2];
    const int*   msk  = (const int*)d_in[3];
    float* ws  = (float*)d_ws;
    float* out = (float*)d_out;

    hipMemsetAsync(d_ws, 0, WS_ZERO * sizeof(float), stream);
    k_counts<<<64, 256, 0, stream>>>(lab, msk, ws);
    k_classsum<<<256, 768, 0, stream>>>(semb, lab, msk, ws);
    k_logits<<<NQ / LB, 256, 0, stream>>>(qemb, ws, out);
}